// Round 16
// baseline (802.898 us; speedup 1.0000x reference)
//
#include <hip/hip_runtime.h>

#define N 2048
#define DIM 64
#define NB 2048
#define PD_RANGE 1024.0f      // fixed hist range; pd <= 4*max||x||^2 ~ 520 << 1024
#define LOG_N 7.624618986159398f

typedef short bf16x8 __attribute__((ext_vector_type(8)));
typedef float f32x4 __attribute__((ext_vector_type(4)));
typedef unsigned short u16x8 __attribute__((ext_vector_type(8)));

// ws layout (bytes)
#define GHIST_OFF 0           // u32[2048]  (zeroed by prep blocks 0-7)
#define SCAL_OFF  8192        // f32[2]: inv_hh, thh (written by hist_k fan-in)
#define CNTH_OFF  8256        // u32 hist fan-in counter (zeroed by prep block 8)
#define SQ_OFF    8448        // f32[2048]
#define XB_OFF    16640       // bf16 XB[N][64] row-major (hist + af)     (262144)
#define XS_OFF    278784      // bf16 XS[N/16][2][16][32] wave-contig X   (262144)
#define WT_OFF    540928      // bf16 WT4[16][4][64][32] wave-contig W^T  (262144)
#define XT_OFF    803072      // bf16 XT4[16][4][64][32] wave-contig X^T  (262144)
#define DUMMY_OFF 1065216     // f32 dummy out [N*64]                     (524288)

__device__ inline float wred64(float v) {
    #pragma unroll
    for (int m = 32; m; m >>= 1) v += __shfl_xor(v, m, 64);
    return v;
}
__device__ inline unsigned short f2bf(float f) {
    unsigned u = __float_as_uint(f);
    return (unsigned short)((u + 0x7FFFu + ((u >> 16) & 1u)) >> 16);
}

// ---------------- prep: zero hist/counter; sq, w, bf16 tables ----------------
__global__ __launch_bounds__(256) void prep_k(const float* __restrict__ x,
                                              const float* __restrict__ mu,
                                              char* __restrict__ ws) {
    unsigned short* XB = (unsigned short*)(ws + XB_OFF);
    unsigned short* XS = (unsigned short*)(ws + XS_OFF);
    unsigned short* WT = (unsigned short*)(ws + WT_OFF);
    unsigned short* XT = (unsigned short*)(ws + XT_OFF);
    float* SQ = (float*)(ws + SQ_OFF);
    unsigned* ghist = (unsigned*)(ws + GHIST_OFF);
    if (blockIdx.x < 8) ghist[blockIdx.x * 256 + threadIdx.x] = 0u;
    if (blockIdx.x == 8 && threadIdx.x == 0) *(unsigned*)(ws + CNTH_OFF) = 0u;
    int w = threadIdx.x >> 6, lane = threadIdx.x & 63;
    int j = blockIdx.x * 4 + w;
    float xv = x[j * DIM + lane];
    float sg = mu[lane] - xv;                       // s_grad
    float sq = wred64(xv * xv);
    float xd = wred64(xv * sg);
    float wv = sg - xv * (xd / sq) - xv * (63.0f / sq);  // D_j s_grad + divD_j
    unsigned short xb = f2bf(xv);
    XB[j * DIM + lane] = xb;
    XS[((j >> 4) * 2 + (lane >> 5)) * 512 + (j & 15) * 32 + (lane & 31)] = xb;
    int bo = (j >> 7) * 8192 + ((j >> 5) & 3) * 2048 + lane * 32 + (j & 31);
    XT[bo] = xb;
    WT[bo] = f2bf(wv);
    if (lane == 0) SQ[j] = sq;
}

// ---------------- histogram (rows subsampled by 4, 1M samples) + fan-in median ----------------
__global__ __launch_bounds__(256) void hist_k(char* __restrict__ ws) {
    __shared__ unsigned short s_xi[128 * 64];
    __shared__ unsigned short s_xj[64 * 64];
    __shared__ float s_sqi[128];
    __shared__ float s_sqj[64];
    __shared__ unsigned s_hist[NB];
    __shared__ unsigned s_flag;
    __shared__ float medv[2];
    const unsigned short* XB = (const unsigned short*)(ws + XB_OFF);
    const float* SQ = (const float*)(ws + SQ_OFF);
    unsigned* ghist = (unsigned*)(ws + GHIST_OFF);
    unsigned* cnth = (unsigned*)(ws + CNTH_OFF);
    float* scal_f = (float*)(ws + SCAL_OFF);
    int tid = threadIdx.x;
    int i0 = (blockIdx.x >> 5) * 128;
    int j0 = (blockIdx.x & 31) * 64;
    for (int b = tid; b < NB; b += 256) s_hist[b] = 0u;
    const u16x8* XBv = (const u16x8*)XB;
    #pragma unroll
    for (int q = 0; q < 4; q++) {
        int idx = tid + q * 256; int r = idx >> 3, c = idx & 7;
        u16x8 v = XBv[(4 * (i0 + r)) * 8 + c];
        int byt = (c * 16) ^ ((r & 7) << 4);
        *(u16x8*)((char*)s_xi + r * 128 + byt) = v;
    }
    #pragma unroll
    for (int q = 0; q < 2; q++) {
        int idx = tid + q * 256; int r = idx >> 3, c = idx & 7;
        u16x8 v = XBv[(j0 + r) * 8 + c];
        int byt = (c * 16) ^ ((r & 7) << 4);
        *(u16x8*)((char*)s_xj + r * 128 + byt) = v;
    }
    if (tid < 128) s_sqi[tid] = SQ[4 * (i0 + tid)];
    if (tid >= 128 && tid < 192) s_sqj[tid - 128] = SQ[j0 + tid - 128];
    const float scale = (float)NB / PD_RANGE;
    __syncthreads();
    int lane = tid & 63, w = tid >> 6, lo = lane & 15, hi = lane >> 4;
    f32x4 acc[2][4];
    #pragma unroll
    for (int a = 0; a < 2; a++)
        #pragma unroll
        for (int b = 0; b < 4; b++) acc[a][b] = (f32x4)0.0f;
    #pragma unroll
    for (int kc = 0; kc < 2; kc++) {
        bf16x8 af[2];
        #pragma unroll
        for (int si = 0; si < 2; si++) {
            int row = w * 32 + si * 16 + lo;
            int byt = (kc * 64 + hi * 16) ^ ((row & 7) << 4);
            af[si] = *(const bf16x8*)((const char*)s_xi + row * 128 + byt);
        }
        #pragma unroll
        for (int sj = 0; sj < 4; sj++) {
            int row = sj * 16 + lo;
            int byt = (kc * 64 + hi * 16) ^ ((row & 7) << 4);
            bf16x8 bfr = *(const bf16x8*)((const char*)s_xj + row * 128 + byt);
            #pragma unroll
            for (int si = 0; si < 2; si++)
                acc[si][sj] = __builtin_amdgcn_mfma_f32_16x16x32_bf16(af[si], bfr, acc[si][sj], 0, 0, 0);
        }
    }
    #pragma unroll
    for (int si = 0; si < 2; si++)
        #pragma unroll
        for (int sj = 0; sj < 4; sj++)
            #pragma unroll
            for (int r = 0; r < 4; r++) {
                int il = w * 32 + si * 16 + hi * 4 + r;
                int jl = sj * 16 + lo;
                float pd = fmaxf(s_sqi[il] + s_sqj[jl] - 2.0f * acc[si][sj][r], 0.0f);
                int bin = min((int)(pd * scale), NB - 1);
                atomicAdd(&s_hist[bin], 1u);
            }
    __syncthreads();
    for (int b = tid; b < NB; b += 256) { unsigned v = s_hist[b]; if (v) atomicAdd(&ghist[b], v); }
    __threadfence();
    if (tid == 0) s_flag = atomicAdd(cnth, 1u);
    __syncthreads();
    if (s_flag == 127u) {
        __threadfence();
        unsigned v[8]; unsigned s = 0;
        #pragma unroll
        for (int b = 0; b < 8; b++) { v[b] = ghist[tid * 8 + b]; s += v[b]; }
        unsigned* csum = s_hist;
        csum[tid] = s;
        __syncthreads();
        #pragma unroll
        for (int off = 1; off < 256; off <<= 1) {
            unsigned t = (tid >= off) ? csum[tid - off] : 0u;
            __syncthreads();
            csum[tid] += t;
            __syncthreads();
        }
        unsigned incl = csum[tid], excl = incl - s;
        const float binw = PD_RANGE / (float)NB;
        const unsigned kqs[2] = { 524287u, 524288u };
        #pragma unroll
        for (int t = 0; t < 2; t++) {
            unsigned kq = kqs[t];
            if (excl <= kq && kq < incl) {
                unsigned a2 = excl; int bin = -1;
                #pragma unroll
                for (int b = 0; b < 8; b++) {
                    unsigned na = a2 + v[b];
                    if (bin < 0 && na > kq) bin = tid * 8 + b;
                    a2 = na;
                }
                medv[t] = ((float)bin + 0.5f) * binw;
            }
        }
        __syncthreads();
        if (tid == 0) {
            float hh = 0.5f * (medv[0] + medv[1]) / LOG_N + 1e-6f;
            scal_f[0] = 1.0f / hh;
            scal_f[1] = 2.0f / hh;
        }
    }
}

// ---- SVGD ablation template: VARIANT 0=full 1=no-gloads 2=no-exp 3=no-LDS-roundtrip ----
template<int VARIANT, int REPEAT>
__global__ __launch_bounds__(1024, 4) void svgd_t(const float* __restrict__ x,
                                                  char* __restrict__ ws,
                                                  float* __restrict__ outp) {
    __shared__ unsigned short s_k[16 * 512];
    __shared__ unsigned short s_c[16 * 512];
    __shared__ float s_red[2 * 8 * 64];
    __shared__ float s_rs[8];
    const unsigned short* XB = (const unsigned short*)(ws + XB_OFF);
    const unsigned short* XS = (const unsigned short*)(ws + XS_OFF);
    const char* WTb = ws + WT_OFF;
    const char* XTb = ws + XT_OFF;
    const float* SQ = (const float*)(ws + SQ_OFF);
    const float* scal_f = (const float*)(ws + SCAL_OFF);
    int tid = threadIdx.x;
    int i0 = blockIdx.x * 8;
    int lane = tid & 63, w = tid >> 6, lo = lane & 15, hi = lane >> 4;

    for (int q = tid; q < 2 * 8 * 64; q += 1024) s_red[q] = 0.f;
    if (tid < 8) s_rs[tid] = 0.f;

    float inv_hh = scal_f[0], thh = scal_f[1];
    float sqi_r[4];
    #pragma unroll
    for (int r = 0; r < 4; r++) { int il = hi * 4 + r; sqi_r[r] = (il < 8) ? SQ[i0 + il] : 0.0f; }
    bf16x8 af[2];
    #pragma unroll
    for (int kc = 0; kc < 2; kc++)
        af[kc] = (lo < 8) ? *(const bf16x8*)(XB + (i0 + lo) * 64 + kc * 32 + hi * 8) : (bf16x8)0;

    f32x4 a1[4], a2[4], rsv;
    #pragma unroll
    for (int sd = 0; sd < 4; sd++) { a1[sd] = (f32x4)0.f; a2[sd] = (f32x4)0.f; }
    rsv = (f32x4)0.f;
    bf16x8 ones;
    #pragma unroll
    for (int e = 0; e < 8; e++) ones[e] = (short)0x3F80;
    float keep = 0.f;
    __syncthreads();

    for (int rep = 0; rep < REPEAT; rep++) {
        for (int itr = 0; itr < 4; itr++) {
            int jw = itr * 512 + w * 32;
            bf16x8 bS[2][2];
            float sqj[2];
            bf16x8 bW[4], bX[4];
            if (VARIANT == 1) {
                #pragma unroll
                for (int sj = 0; sj < 2; sj++)
                    #pragma unroll
                    for (int kc = 0; kc < 2; kc++) bS[sj][kc] = af[kc];
                sqj[0] = 1.0f; sqj[1] = 1.0f;
                #pragma unroll
                for (int sd = 0; sd < 4; sd++) { bW[sd] = af[0]; bX[sd] = af[1]; }
            } else {
                #pragma unroll
                for (int sj = 0; sj < 2; sj++) {
                    int g = (jw >> 4) + sj;
                    #pragma unroll
                    for (int kc = 0; kc < 2; kc++)
                        bS[sj][kc] = *(const bf16x8*)(XS + (g * 2 + kc) * 512 + lo * 32 + hi * 8);
                }
                sqj[0] = SQ[jw + lo];
                sqj[1] = SQ[jw + 16 + lo];
                const char* wtb = WTb + (jw >> 7) * 16384 + ((jw >> 5) & 3) * 4096;
                const char* xtb = XTb + (jw >> 7) * 16384 + ((jw >> 5) & 3) * 4096;
                #pragma unroll
                for (int sd = 0; sd < 4; sd++) {
                    int off = (sd * 16 + lo) * 64 + hi * 16;
                    bW[sd] = *(const bf16x8*)(wtb + off);
                    bX[sd] = *(const bf16x8*)(xtb + off);
                }
            }
            // S = X_I . X_J^T
            f32x4 sreg[2]; sreg[0] = (f32x4)0.f; sreg[1] = (f32x4)0.f;
            #pragma unroll
            for (int kc = 0; kc < 2; kc++)
                #pragma unroll
                for (int sj = 0; sj < 2; sj++)
                    sreg[sj] = __builtin_amdgcn_mfma_f32_16x16x32_bf16(af[kc], bS[sj][kc], sreg[sj], 0, 0, 0);
            // K, C
            #pragma unroll
            for (int sj = 0; sj < 2; sj++) {
                float rq = 1.0f / sqj[sj];
                #pragma unroll
                for (int r = 0; r < 4; r++) {
                    int il = hi * 4 + r;
                    float dot = sreg[sj][r];
                    float pd = fmaxf(sqi_r[r] + sqj[sj] - 2.0f * dot, 0.0f);
                    float kv, cv;
                    if (VARIANT == 2) { kv = pd * 0.0009765625f + 0.1f; cv = kv * dot * rq; }
                    else { kv = __expf(-pd * inv_hh); cv = kv * dot * rq; }
                    if (VARIANT == 3) {
                        keep += kv + cv;          // keep exp alive (rule #17)
                    } else {
                        int byt = (w * 64 + sj * 32 + lo * 2) ^ ((il & 7) << 4);
                        *(unsigned short*)((char*)s_k + il * 1024 + byt) = f2bf(kv);
                        *(unsigned short*)((char*)s_c + il * 1024 + byt) = f2bf(cv);
                    }
                }
            }
            bf16x8 aK, aC;
            if (VARIANT == 3) {
                aK = bS[0][0]; aC = bS[0][1];
            } else {
                int bytK = (w * 64 + hi * 16) ^ ((lo & 7) << 4);
                aK = *(const bf16x8*)((const char*)s_k + lo * 1024 + bytK);
                aC = *(const bf16x8*)((const char*)s_c + lo * 1024 + bytK);
            }
            #pragma unroll
            for (int sd = 0; sd < 4; sd++) {
                a1[sd] = __builtin_amdgcn_mfma_f32_16x16x32_bf16(aK, bW[sd], a1[sd], 0, 0, 0);
                a2[sd] = __builtin_amdgcn_mfma_f32_16x16x32_bf16(aC, bX[sd], a2[sd], 0, 0, 0);
            }
            rsv = __builtin_amdgcn_mfma_f32_16x16x32_bf16(aK, ones, rsv, 0, 0, 0);
        }
    }
    if (VARIANT == 3) asm volatile("" :: "v"(keep));

    #pragma unroll
    for (int sd = 0; sd < 4; sd++)
        #pragma unroll
        for (int r = 0; r < 4; r++) {
            int il = hi * 4 + r;
            if (il < 8) {
                int dd = sd * 16 + lo;
                atomicAdd(&s_red[il * 64 + dd], a1[sd][r]);
                atomicAdd(&s_red[8 * 64 + il * 64 + dd], a2[sd][r]);
            }
        }
    if (lo == 0) {
        #pragma unroll
        for (int r = 0; r < 4; r++) {
            int il = hi * 4 + r;
            if (il < 8) atomicAdd(&s_rs[il], rsv[r]);
        }
    }
    __syncthreads();

    if (w < 8) {
        int row = i0 + w;
        float xv = x[row * DIM + lane];
        float sqi = SQ[row];
        float acc1 = s_red[w * 64 + lane];
        float acc2 = s_red[8 * 64 + w * 64 + lane];
        float rs = s_rs[w];
        float inner = acc1 + (rs * xv - acc2) * thh;
        float xin = wred64(xv * inner);
        float gr = inner - xv * ((xin + 63.0f) / sqi);
        float dx = gr * (0.1f / (float)N);
        dx = fminf(fmaxf(dx, -1000.0f), 1000.0f);
        outp[row * DIM + lane] = xv + dx;
    }
}

extern "C" void kernel_launch(void* const* d_in, const int* in_sizes, int n_in,
                              void* d_out, int out_size, void* d_ws, size_t ws_size,
                              hipStream_t stream) {
    const float* x  = (const float*)d_in[0];
    const float* mu = (const float*)d_in[1];
    float* out = (float*)d_out;
    char* ws = (char*)d_ws;
    float* dummy = (float*)(ws + DUMMY_OFF);

    prep_k<<<N / 4, 256, 0, stream>>>(x, mu, ws);
    hist_k<<<(512 / 128) * (N / 64), 256, 0, stream>>>(ws);
    // ---- ablation probes (x4 repeat so each lands in rocprof top-5) ----
    svgd_t<0, 4><<<N / 8, 1024, 0, stream>>>(x, ws, dummy);   // full
    svgd_t<1, 4><<<N / 8, 1024, 0, stream>>>(x, ws, dummy);   // no global operand loads
    svgd_t<2, 4><<<N / 8, 1024, 0, stream>>>(x, ws, dummy);   // no __expf
    svgd_t<3, 4><<<N / 8, 1024, 0, stream>>>(x, ws, dummy);   // no LDS roundtrip
    // ---- the real one ----
    svgd_t<0, 1><<<N / 8, 1024, 0, stream>>>(x, ws, out);
}